// Round 6
// baseline (299.534 us; speedup 1.0000x reference)
//
#include <hip/hip_runtime.h>

// B=2, T=2048, C=1024, H=16, d=64. Inputs/outputs fp32; internal bf16 MFMA.
typedef unsigned short u16;
typedef u16   u16x4  __attribute__((ext_vector_type(4)));
typedef u16   u16x8  __attribute__((ext_vector_type(8)));
typedef __bf16 bf16x8 __attribute__((ext_vector_type(8)));
typedef float  f32x4  __attribute__((ext_vector_type(4)));

__device__ __forceinline__ float bf2f(u16 v) {
    unsigned u = ((unsigned)v) << 16;
    return __builtin_bit_cast(float, u);
}
__device__ __forceinline__ u16 f2bf(float f) {
    unsigned u = __builtin_bit_cast(unsigned, f);
    u += 0x7fffu + ((u >> 16) & 1u);   // RNE
    return (u16)(u >> 16);
}

// Async global->LDS DMA, 16B per lane. LDS dest is lane-linear
// (wave-uniform base + lane*16B). Global src is image-linear => coalesced.
__device__ __forceinline__ void async16(const u16* g, u16* l) {
    __builtin_amdgcn_global_load_lds(
        (const __attribute__((address_space(1))) unsigned int*)g,
        (__attribute__((address_space(3))) unsigned int*)l,
        16, 0, 0);
}

// Packed operand images: per (bh, 64-s-chunk) a 512-slot x 8-elem tile (4096 u16).
// K-operand image (k=d): slot = (d>>3)*64 + (s&63), elem = d&7
__device__ __forceinline__ size_t kimg_idx(int bh, int s, int d) {
    return ((size_t)(bh * 32 + (s >> 6)) * 4096) + (size_t)(((d >> 3) * 64 + (s & 63)) * 8) + (d & 7);
}
// V-operand image (k=s): slot = ((s&63)>>3)*64 + d, elem = s&7
__device__ __forceinline__ size_t vimg_idx(int bh, int s, int d) {
    return ((size_t)(bh * 32 + (s >> 6)) * 4096) + (size_t)((((s & 63) >> 3) * 64 + d) * 8) + (s & 7);
}

// GEMM DMA-images: per (128-row-tile, 32-k-slab) a contiguous 4096-u16 block
// whose slot order equals the GEMM LDS layout [kk][row] -> coalesced DMA.
__device__ __forceinline__ size_t g128_idx(int m, int k) {
    return ((size_t)((m >> 7) * 32 + (k >> 5)) * 4096)
         + (size_t)((((k >> 3) & 3) * 128 + (m & 127)) * 8 + (k & 7));
}
// BM=64 tiles (A of gemm64): block = 2048 u16.
__device__ __forceinline__ size_t g64_idx(int m, int k) {
    return ((size_t)((m >> 6) * 32 + (k >> 5)) * 2048)
         + (size_t)((((k >> 3) & 3) * 64 + (m & 63)) * 8 + (k & 7));
}

// ---------------------------------------------------------------------------
// fp32 x -> bf16 row-major xb, V-image xpack, AND GEMM A-image agimg.
// ---------------------------------------------------------------------------
__global__ __launch_bounds__(256)
void convert_pack(const float* __restrict__ in, u16* __restrict__ xb,
                  u16* __restrict__ xpack, u16* __restrict__ agimg) {
    int i = blockIdx.x * 256 + threadIdx.x;       // [0, 1048576)
    int c4 = i & 255, row = i >> 8;               // row = b*2048 + s
    int s = row & 2047, b = row >> 11;
    float4 v = ((const float4*)in)[i];
    u16x4 o;
    o.x = f2bf(v.x); o.y = f2bf(v.y); o.z = f2bf(v.z); o.w = f2bf(v.w);
    ((u16x4*)xb)[i] = o;
    int h = c4 >> 4, d0 = (c4 & 15) * 4;
    size_t base = vimg_idx(b * 16 + h, s, d0);
    xpack[base]      = o.x;
    xpack[base + 8]  = o.y;
    xpack[base + 16] = o.z;
    xpack[base + 24] = o.w;
    int k0 = c4 * 4;                              // k0&7 in {0,4}: u16x4 contiguous
    *(u16x4*)&agimg[g128_idx(row, k0)] = o;
}

// ---------------------------------------------------------------------------
// Weight transposes -> GEMM B-images. grid (64,16).
// bgimg: fused-B image over n in [0,3072) (Wa rows 0..2047, Wk rows 2048..3071).
// bpimg: proj-B image over n in [0,1024).
// ---------------------------------------------------------------------------
__global__ __launch_bounds__(256)
void prep_weights(const float* __restrict__ Wa, const float* __restrict__ Wk,
                  const float* __restrict__ Wp, u16* __restrict__ bgimg,
                  u16* __restrict__ bpimg) {
    __shared__ u16 tile[64][65];
    const int bx = blockIdx.x;
    const float* in; u16* img; int Cd, c0, nbase;
    if (bx < 32)      { in = Wa; img = bgimg; Cd = 2048; c0 = bx * 64;        nbase = c0; }
    else if (bx < 48) { in = Wk; img = bgimg; Cd = 1024; c0 = (bx - 32) * 64; nbase = 2048 + c0; }
    else              { in = Wp; img = bpimg; Cd = 1024; c0 = (bx - 48) * 64; nbase = c0; }
    const int r0 = blockIdx.y * 64;               // k-base
    const int tid = threadIdx.x;
#pragma unroll
    for (int i = 0; i < 16; ++i) {
        int idx = tid + i * 256;
        int r = idx >> 6, c = idx & 63;
        tile[r][c] = f2bf(in[(size_t)(r0 + r) * Cd + c0 + c]);
    }
    __syncthreads();
#pragma unroll
    for (int i = 0; i < 16; ++i) {
        int idx = tid + i * 256;
        int r = idx >> 6, c = idx & 63;
        int n = nbase + r, k = r0 + c;
        img[g128_idx(n, k)] = tile[c][r];
    }
}

// ---------------------------------------------------------------------------
// Fused GEMM: [4096 x 3072] = x @ [W_attn ; W_k2] via DMA-images.
// 256x256 tile, 512 threads (8 waves, 2Mx4N, 128x64 out/wave). LDS 128 KB:
// [buf2][slab2][half2][4096] per operand; each (slab,half) = one contiguous
// image chunk staged by one async16/thread. Deep pipeline (T3+T4): per phase
// { issue 4 DMA for iter+1 -> vmcnt(8) (counted, never 0 mid-loop) ->
//   barrier -> ds_read + setprio(1) 32 MFMA setprio(0) -> barrier }.
// 2 phases/iter (64 k), 16 iters. Grid (12,16) = 192 blocks, 1 block/CU.
// Epilogue: n<1024 -> qs*0.125; n<2048 -> kpack; else sigmoid -> kapack.
// ---------------------------------------------------------------------------
__global__ __launch_bounds__(512, 1)
void gemm_fused(const u16* __restrict__ Aimg, const u16* __restrict__ Bimg,
                u16* __restrict__ qs, u16* __restrict__ kpack,
                u16* __restrict__ kapack) {
    const int NI = 16;                                   // K iters of 64
    __shared__ __align__(16) u16 As[2][2][2][4096];      // [buf][slab][half][kk*128*8]
    __shared__ __align__(16) u16 Bs[2][2][2][4096];
    const int tid = threadIdx.x;
    const int wave = tid >> 6, lane = tid & 63;
    const int wm = (wave >> 2) * 128, wn = (wave & 3) * 64;
    const int ha = wm >> 7;                              // wave's A half (0/1)
    const int hb = wn >> 7;                              // wave's B half (0/1)
    const int wnr = wn & 127;
    const int q = lane >> 4, mr = lane & 15;

    const u16* gA0 = Aimg + (size_t)(2 * blockIdx.y) * 32 * 4096 + tid * 8;
    const u16* gA1 = Aimg + (size_t)(2 * blockIdx.y + 1) * 32 * 4096 + tid * 8;
    const u16* gB0 = Bimg + (size_t)(2 * blockIdx.x) * 32 * 4096 + tid * 8;
    const u16* gB1 = Bimg + (size_t)(2 * blockIdx.x + 1) * 32 * 4096 + tid * 8;
    u16* const lA = &As[0][0][0][0];
    u16* const lB = &Bs[0][0][0][0];
    const int dd = tid * 8;

    f32x4 acc[8][4];
#pragma unroll
    for (int i = 0; i < 8; ++i)
#pragma unroll
        for (int j = 0; j < 4; ++j) acc[i][j] = f32x4{0.f, 0.f, 0.f, 0.f};

    // issue one 32-k slab (global slab idx t2) into (buf b, slot s): 4 DMA/thread
    auto issue = [&](int t2, int b, int s) {
        const int go = t2 * 4096;
        const int lo = ((b * 2 + s) * 2) * 4096;         // half-0 base
        async16(gA0 + go, lA + lo + dd);
        async16(gA1 + go, lA + lo + 4096 + dd);
        async16(gB0 + go, lB + lo + dd);
        async16(gB1 + go, lB + lo + 4096 + dd);
    };
    issue(0, 0, 0);
    issue(1, 0, 1);

    int cb = 0;
    for (int t = 0; t < NI; ++t) {
#pragma unroll
        for (int s = 0; s < 2; ++s) {
            const bool more = (t + 1 < NI);
            if (more) issue((t + 1) * 2 + s, cb ^ 1, s);
            if (more)       asm volatile("s_waitcnt vmcnt(8)" ::: "memory");
            else if (s == 0) asm volatile("s_waitcnt vmcnt(4)" ::: "memory");
            else            asm volatile("s_waitcnt vmcnt(0)" ::: "memory");
            __syncthreads();                             // slab (t,s) visible to all
            const u16* pa = lA + (size_t)(((cb * 2 + s) * 2 + ha) * 4096);
            const u16* pb = lB + (size_t)(((cb * 2 + s) * 2 + hb) * 4096);
            bf16x8 af[8], bfr[4];
#pragma unroll
            for (int i = 0; i < 8; ++i)
                af[i]  = *(const bf16x8*)(pa + (size_t)(q * 128 + i * 16 + mr) * 8);
#pragma unroll
            for (int j = 0; j < 4; ++j)
                bfr[j] = *(const bf16x8*)(pb + (size_t)(q * 128 + wnr + j * 16 + mr) * 8);
            __builtin_amdgcn_s_setprio(1);
#pragma unroll
            for (int i = 0; i < 8; ++i)
#pragma unroll
                for (int j = 0; j < 4; ++j)
                    acc[i][j] = __builtin_amdgcn_mfma_f32_16x16x32_bf16(af[i], bfr[j], acc[i][j], 0, 0, 0);
            __builtin_amdgcn_s_setprio(0);
            __syncthreads();                             // free (cb,s) for reuse
        }
        cb ^= 1;
    }
#pragma unroll
    for (int i = 0; i < 8; ++i)
#pragma unroll
        for (int j = 0; j < 4; ++j)
#pragma unroll
            for (int r = 0; r < 4; ++r) {
                int m = blockIdx.y * 256 + wm + i * 16 + q * 4 + r;
                int n = blockIdx.x * 256 + wn + j * 16 + mr;
                float v = acc[i][j][r];
                int b = m >> 11, s = m & 2047;
                if (n < 1024) {
                    qs[(size_t)m * 1024 + n] = f2bf(v * 0.125f);
                } else if (n < 2048) {
                    int nn = n - 1024;
                    kpack[kimg_idx(b * 16 + (nn >> 6), s, nn & 63)] = f2bf(v);
                } else {
                    int nn = n - 2048;
                    kapack[kimg_idx(b * 16 + (nn >> 6), s, nn & 63)] =
                        f2bf(1.f / (1.f + __expf(-0.0025f * v)));
                }
            }
}

// ---------------------------------------------------------------------------
// 64x128-tile GEMM (proj): fp32 row-major out, DMA-image sources. Triple-
// buffered depth-2 counted-vmcnt pipeline (3 ops/slab). grid (8,64).
// ---------------------------------------------------------------------------
__global__ __launch_bounds__(256, 2)
void gemm64(const u16* __restrict__ Aimg, const u16* __restrict__ Bimg,
            float* __restrict__ Cv, int N, int K) {
    const int NT = 32;
    __shared__ __align__(16) u16 As[3][4][64][8];    // 2048 u16/buf
    __shared__ __align__(16) u16 Bs[3][4][128][8];   // 4096 u16/buf
    const int tid = threadIdx.x;
    const int wave = tid >> 6, lane = tid & 63;
    const int m0 = blockIdx.y * 64, n0 = blockIdx.x * 128;
    const int wn0 = wave * 32;
    const int q = lane >> 4, mr = lane & 15;

    const u16* gA = Aimg + (size_t)blockIdx.y * 32 * 2048;
    const u16* gB = Bimg + (size_t)blockIdx.x * 32 * 4096;
    u16* const lA = &As[0][0][0][0];
    u16* const lB = &Bs[0][0][0][0];
    const int d0 = tid * 8, d1 = (256 + tid) * 8;

    f32x4 acc[4][2];
#pragma unroll
    for (int i = 0; i < 4; ++i)
#pragma unroll
        for (int j = 0; j < 2; ++j) acc[i][j] = f32x4{0.f, 0.f, 0.f, 0.f};

    // prologue: slabs 0,1 -> bufs 0,1 (6 DMA ops/wave)
    async16(gA + d0,        lA + d0);
    async16(gB + d0,        lB + d0);
    async16(gB + d1,        lB + d1);
    async16(gA + 2048 + d0, lA + 2048 + d0);
    async16(gB + 4096 + d0, lB + 4096 + d0);
    async16(gB + 4096 + d1, lB + 4096 + d1);

    int coA = 0, coB = 0, ioA = 2 * 2048, ioB = 2 * 4096;
    for (int t = 0; t < NT; ++t) {
        if (t < NT - 1) asm volatile("s_waitcnt vmcnt(3)" ::: "memory");
        else            asm volatile("s_waitcnt vmcnt(0)" ::: "memory");
        __syncthreads();
        if (t + 2 < NT) {
            async16(gA + (t + 2) * 2048 + d0, lA + ioA + d0);
            async16(gB + (t + 2) * 4096 + d0, lB + ioB + d0);
            async16(gB + (t + 2) * 4096 + d1, lB + ioB + d1);
        }
        bf16x8 af[4], bfr[2];
#pragma unroll
        for (int i = 0; i < 4; ++i)
            af[i]  = *(const bf16x8*)(lA + coA + (size_t)(q * 64 + i * 16 + mr) * 8);
#pragma unroll
        for (int j = 0; j < 2; ++j)
            bfr[j] = *(const bf16x8*)(lB + coB + (size_t)(q * 128 + wn0 + j * 16 + mr) * 8);
#pragma unroll
        for (int i = 0; i < 4; ++i)
#pragma unroll
            for (int j = 0; j < 2; ++j)
                acc[i][j] = __builtin_amdgcn_mfma_f32_16x16x32_bf16(af[i], bfr[j], acc[i][j], 0, 0, 0);
        coA += 2048; if (coA == 3 * 2048) coA = 0;
        coB += 4096; if (coB == 3 * 4096) coB = 0;
        ioA += 2048; if (ioA == 3 * 2048) ioA = 0;
        ioB += 4096; if (ioB == 3 * 4096) ioB = 0;
    }
#pragma unroll
    for (int i = 0; i < 4; ++i)
#pragma unroll
        for (int j = 0; j < 2; ++j)
#pragma unroll
            for (int r = 0; r < 4; ++r) {
                int m = m0 + i * 16 + q * 4 + r;
                int n = n0 + wn0 + j * 16 + mr;
                Cv[(size_t)m * N + n] = acc[i][j][r];
            }
}

// ---------------------------------------------------------------------------
// Flash attention: 128-row t-tiles (2 m-tiles/wave: {w, w+4}), s-split (z =
// chunk parity). Block bx handles tile pair {bx, 15-bx}. Static mt unroll
// (dynamic bounds caused scratch demotion in R7).
// ---------------------------------------------------------------------------
__global__ __launch_bounds__(256, 2)
void flash_mfma(const u16* __restrict__ qs, const u16* __restrict__ kpack,
                const u16* __restrict__ xpack, u16* __restrict__ Opart,
                float* __restrict__ lpart) {
    __shared__ __align__(16) u16 Ks[8][64][8];
    __shared__ __align__(16) u16 Vs[8][64][8];
    __shared__ __align__(16) u16 Ps[4][16][72];
    const int bh = blockIdx.y, b = bh >> 4, hc = (bh & 15) * 64;
    const int z = blockIdx.z;
    const int tid = threadIdx.x, w = tid >> 6, lane = tid & 63;
    const int n16 = lane & 15, quad = lane >> 4;
    const u16* kbase = kpack + (size_t)bh * 32 * 4096;
    const u16* vbase = xpack + (size_t)bh * 32 * 4096;
    u16* Ob = Opart + (size_t)z * 4096 * 1024;
    float* lb = lpart + z * 65536;

    for (int rep = 0; rep < 2; ++rep) {
        const int T = rep ? 15 - (int)blockIdx.x : (int)blockIdx.x;
        const int t0 = T * 128;
        const int nchunk = 2 * T + 2;

        bf16x8 qf[2][2];
#pragma unroll
        for (int mt = 0; mt < 2; ++mt) {
            const int trow = t0 + (w + mt * 4) * 16 + n16;
            const u16* qp = &qs[(size_t)(b * 2048 + trow) * 1024 + hc + quad * 8];
            qf[mt][0] = *(const bf16x8*)qp;
            qf[mt][1] = *(const bf16x8*)(qp + 32);
        }

        f32x4 O[2][4];
        float lsum[2][4];
#pragma unroll
        for (int mt = 0; mt < 2; ++mt)
#pragma unroll
            for (int jt = 0; jt < 4; ++jt) { O[mt][jt] = f32x4{0.f, 0.f, 0.f, 0.f}; }
#pragma unroll
        for (int mt = 0; mt < 2; ++mt)
#pragma unroll
            for (int r = 0; r < 4; ++r) lsum[mt][r] = 0.f;

        u16x8 kr0, kr1, vr0, vr1;
        auto pref = [&](int c) {
            const u16* kc = kbase + (size_t)c * 4096;
            const u16* vc = vbase + (size_t)c * 4096;
            kr0 = *(const u16x8*)(kc + tid * 8);
            kr1 = *(const u16x8*)(kc + (256 + tid) * 8);
            vr0 = *(const u16x8*)(vc + tid * 8);
            vr1 = *(const u16x8*)(vc + (256 + tid) * 8);
        };
        if (z < nchunk) pref(z);

        for (int c = z; c < nchunk; c += 2) {
            __syncthreads();
            *(u16x8*)((u16*)Ks + tid * 8)         = kr0;
            *(u16x8*)((u16*)Ks + (256 + tid) * 8) = kr1;
            *(u16x8*)((u16*)Vs + tid * 8)         = vr0;
            *(u16x8*)((u16*)Vs + (256 + tid) * 8) = vr1;
            __syncthreads();
            if (c + 2 < nchunk) pref(c + 2);

            f32x4 S[2][4];
#pragma unroll
            for (int mt = 0; mt < 2; ++mt)
#pragma unroll
                for (int jt = 0; jt < 4; ++jt) S[mt][jt] = f32x4{0.f, 0.f, 0.f, 0.f};
#pragma unroll
            for (int ks = 0; ks < 2; ++ks)
#pragma unroll
                for (int jt = 0; jt < 4; ++jt) {
                    bf16x8 kf = *(const bf16x8*)&Ks[ks * 4 + quad][jt * 16 + n16][0];
                    S[0][jt] = __builtin_amdgcn_mfma_f32_16x16x32_bf16(qf[0][ks], kf, S[0][jt], 0, 0, 0);
                    S[1][jt] = __builtin_amdgcn_mfma_f32_16x16x32_bf16(qf[1][ks], kf, S[1][jt], 0, 0, 0);
                }
            bf16x8 vf[2][4];
#pragma unroll
            for (int ks = 0; ks < 2; ++ks)
#pragma unroll
                for (int jt = 0; jt < 4; ++jt)
                    vf[ks][jt] = *(const bf16x8*)&Vs[ks * 4 + quad][jt * 16 + n16][0];

#pragma unroll
            for (int mt = 0; mt < 2; ++mt) {
                if (mt == 0 && c == 2 * T + 1) continue;   // fully-masked subtile
                float p[4][4];
#pragma unroll
                for (int reg = 0; reg < 4; ++reg)
#pragma unroll
                    for (int jt = 0; jt < 4; ++jt)
                        p[reg][jt] = __expf(S[mt][jt][reg]);
                if (c == 2 * T + mt) {   // partially-masked diagonal subtile
#pragma unroll
                    for (int reg = 0; reg < 4; ++reg) {
                        const int tr = t0 + (w + mt * 4) * 16 + quad * 4 + reg;
#pragma unroll
                        for (int jt = 0; jt < 4; ++jt)
                            if (c * 64 + jt * 16 + n16 > tr) p[reg][jt] = 0.f;
                    }
                }
#pragma unroll
                for (int reg = 0; reg < 4; ++reg) {
                    lsum[mt][reg] += (p[reg][0] + p[reg][1]) + (p[reg][2] + p[reg][3]);
#pragma unroll
                    for (int jt = 0; jt < 4; ++jt)
                        Ps[w][quad * 4 + reg][jt * 16 + n16] = f2bf(p[reg][jt]);
                }
                bf16x8 pf[2];
#pragma unroll
                for (int ks = 0; ks < 2; ++ks)
                    pf[ks] = *(const bf16x8*)&Ps[w][n16][ks * 32 + quad * 8];
#pragma unroll
                for (int ks = 0; ks < 2; ++ks)
#pragma unroll
                    for (int jt = 0; jt < 4; ++jt)
                        O[mt][jt] = __builtin_amdgcn_mfma_f32_16x16x32_bf16(pf[ks], vf[ks][jt], O[mt][jt], 0, 0, 0);
            }
        }

#pragma unroll
        for (int mt = 0; mt < 2; ++mt)
#pragma unroll
            for (int reg = 0; reg < 4; ++reg) {
                float l = lsum[mt][reg];
#pragma unroll
                for (int off = 1; off < 16; off <<= 1) l += __shfl_xor(l, off, 64);
                const int tr = t0 + (w + mt * 4) * 16 + quad * 4 + reg;
                if (n16 == 0) lb[bh * 2048 + tr] = l;
                const size_t row = (size_t)(b * 2048 + tr) * 1024 + hc;
#pragma unroll
                for (int jt = 0; jt < 4; ++jt)
                    Ob[row + jt * 16 + n16] = f2bf(O[mt][jt][reg]);
            }
    }
}

// ---------------------------------------------------------------------------
// combine flash halves: y = (O0+O1)/(l0+l1); epack = V-image of x[t+1]-y[t].
// ---------------------------------------------------------------------------
__global__ __launch_bounds__(256)
void combine_flash(const u16* __restrict__ Opart, const float* __restrict__ lpart,
                   const u16* __restrict__ xb, u16* __restrict__ y,
                   u16* __restrict__ epack) {
    int i = blockIdx.x * 256 + threadIdx.x;
    int c4 = i & 255, row = i >> 8, t = row & 2047, b = row >> 11;
    int h = c4 >> 4, d0 = (c4 & 15) * 4;
    size_t off = (size_t)row * 1024 + c4 * 4;
    u16x4 o0 = *(const u16x4*)&Opart[off];
    u16x4 o1 = *(const u16x4*)&Opart[(size_t)4096 * 1024 + off];
    int lrow = (b * 16 + h) * 2048 + t;
    float inv = 1.f / (lpart[lrow] + lpart[65536 + lrow]);
    float y0 = (bf2f(o0.x) + bf2f(o1.x)) * inv;
    float y1 = (bf2f(o0.y) + bf2f(o1.y)) * inv;
    float y2 = (bf2f(o0.z) + bf2f(o1.z)) * inv;
    float y3 = (bf2f(o0.w) + bf2f(o1.w)) * inv;
    u16x4 yo;
    yo.x = f2bf(y0); yo.y = f2bf(y1); yo.z = f2bf(y2); yo.w = f2bf(y3);
    *(u16x4*)&y[off] = yo;
    float e0 = 0.f, e1 = 0.f, e2 = 0.f, e3 = 0.f;
    if (t < 2047) {
        u16x4 xv = *(const u16x4*)&xb[off + 1024];
        e0 = bf2f(xv.x) - y0; e1 = bf2f(xv.y) - y1;
        e2 = bf2f(xv.z) - y2; e3 = bf2f(xv.w) - y3;
    }
    size_t base = vimg_idx(b * 16 + h, t, d0);
    epack[base]      = f2bf(e0);
    epack[base + 8]  = f2bf(e1);
    epack[base + 16] = f2bf(e2);
    epack[base + 24] = f2bf(e3);
}

// ---------------------------------------------------------------------------
// ARMA, same 128-row structure, strict mask, no softmax. Static mt unroll.
// ---------------------------------------------------------------------------
__global__ __launch_bounds__(256, 2)
void arma_mfma(const u16* __restrict__ qs, const u16* __restrict__ kapack,
               const u16* __restrict__ epack, u16* __restrict__ Opart) {
    __shared__ __align__(16) u16 Ks[8][64][8];
    __shared__ __align__(16) u16 Es[8][64][8];
    __shared__ __align__(16) u16 Ps[4][16][72];
    const int bh = blockIdx.y, b = bh >> 4, hc = (bh & 15) * 64;
    const int z = blockIdx.z;
    const int tid = threadIdx.x, w = tid >> 6, lane = tid & 63;
    const int n16 = lane & 15, quad = lane >> 4;
    const u16* kbase = kapack + (size_t)bh * 32 * 4096;
    const u16* vbase = epack + (size_t)bh * 32 * 4096;
    u16* Ob = Opart + (size_t)z * 4096 * 1024;

    for (int rep = 0; rep < 2; ++rep) {
        const int T = rep ? 15 - (int)blockIdx.x : (int)blockIdx.x;
        const int t0 = T * 128;
        const int nchunk = 2 * T + 2;

        bf16x8 qf[2][2];
#pragma unroll
        for (int mt = 0; mt < 2; ++mt) {
            const int trow = t0 + (w + mt * 4) * 16 + n16;
            const u16* qp = &qs[(size_t)(b * 2048 + trow) * 1024 + hc + quad * 8];
#pragma unroll
            for (int ks = 0; ks < 2; ++ks) {
                u16x8 qv = *(const u16x8*)(qp + ks * 32);
                u16x8 o;
#pragma unroll
                for (int j = 0; j < 8; ++j) {
                    float zv = bf2f(qv[j]);              // pre-scaled by 1/8
                    o[j] = f2bf(zv < 0.f ? zv : 0.02f * zv);
                }
                qf[mt][ks] = __builtin_bit_cast(bf16x8, o);
            }
        }

        f32x4 O[2][4];
#pragma unroll
        for (int mt = 0; mt < 2; ++mt)
#pragma unroll
            for (int jt = 0; jt < 4; ++jt) O[mt][jt] = f32x4{0.f, 0.f, 0.f, 0.f};

        u16x8 kr0, kr1, vr0, vr1;
        auto pref = [&](int c) {
            const u16* kc = kbase + (size_t)c * 4096;
            const u16* vc = vbase + (size_t)c * 4096;
            kr0 = *(const u16x8*)(kc + tid * 8);
            kr1 = *(const u16x8*)(kc + (256 + tid) * 8);
            vr0 = *(const u16x8*)(vc + tid * 8);
            vr1 = *(const u16x8*)(vc + (256 + tid) * 8);
        };
        if (z < nchunk) pref(z);

        for (int c = z; c < nchunk; c += 2) {
            __syncthreads();
            *(u16x8*)((u16*)Ks + tid * 8)         = kr0;
            *(u16x8*)((u16*)Ks + (256 + tid) * 8) = kr1;
            *(u16x8*)((u16*)Es + tid * 8)         = vr0;
            *(u16x8*)((u16*)Es + (256 + tid) * 8) = vr1;
            __syncthreads();
            if (c + 2 < nchunk) pref(c + 2);

            f32x4 S[2][4];
#pragma unroll
            for (int mt = 0; mt < 2; ++mt)
#pragma unroll
                for (int jt = 0; jt < 4; ++jt) S[mt][jt] = f32x4{0.f, 0.f, 0.f, 0.f};
#pragma unroll
            for (int ks = 0; ks < 2; ++ks)
#pragma unroll
                for (int jt = 0; jt < 4; ++jt) {
                    bf16x8 kf = *(const bf16x8*)&Ks[ks * 4 + quad][jt * 16 + n16][0];
                    S[0][jt] = __builtin_amdgcn_mfma_f32_16x16x32_bf16(qf[0][ks], kf, S[0][jt], 0, 0, 0);
                    S[1][jt] = __builtin_amdgcn_mfma_f32_16x16x32_bf16(qf[1][ks], kf, S[1][jt], 0, 0, 0);
                }
            bf16x8 vf[2][4];
#pragma unroll
            for (int ks = 0; ks < 2; ++ks)
#pragma unroll
                for (int jt = 0; jt < 4; ++jt)
                    vf[ks][jt] = *(const bf16x8*)&Es[ks * 4 + quad][jt * 16 + n16][0];

#pragma unroll
            for (int mt = 0; mt < 2; ++mt) {
                if (mt == 0 && c == 2 * T + 1) continue;   // fully-masked subtile
                if (c == 2 * T + mt) {   // strict mask s < t on diagonal subtile
#pragma unroll
                    for (int reg = 0; reg < 4; ++reg) {
                        const int tr = t0 + (w + mt * 4) * 16 + quad * 4 + reg;
#pragma unroll
                        for (int jt = 0; jt < 4; ++jt)
                            if (c * 64 + jt * 16 + n16 >= tr) S[mt][jt][reg] = 0.f;
                    }
                }
#pragma unroll
                for (int reg = 0; reg < 4; ++reg)
#pragma unroll
                    for (int jt = 0; jt < 4; ++jt)
                        Ps[w][quad * 4 + reg][jt * 16 + n16] = f2bf(S[mt][jt][reg]);
                bf16x8 pf[2];
#pragma unroll
                for (int ks = 0; ks < 2; ++ks)
                    pf[ks] = *(const bf16x8*)&Ps[w][n16][ks * 32 + quad * 8];
#pragma unroll
                for (int ks = 0; ks < 2; ++ks)
#pragma unroll
                    for (int jt = 0; jt < 4; ++jt)
                        O[mt][jt] = __builtin_amdgcn_mfma_f32_16x16x32_bf16(pf[ks], vf[ks][jt], O[mt][jt], 0, 0, 0);
            }
        }

#pragma unroll
        for (int mt = 0; mt < 2; ++mt)
#pragma unroll
            for (int reg = 0; reg < 4; ++reg) {
                const int tr = t0 + (w + mt * 4) * 16 + quad * 4 + reg;
                const size_t row = (size_t)(b * 2048 + tr) * 1024 + hc;
#pragma unroll
                for (int jt = 0; jt < 4; ++jt)
                    Ob[row + jt * 16 + n16] = f2bf(O[mt][jt][reg]);
            }
    }
}

// ---------------------------------------------------------------------------
// combine arma halves: ysimg = A-image (BM=64) of y + O0 + O1 (bf16).
// ---------------------------------------------------------------------------
__global__ __launch_bounds__(256)
void combine_arma(const u16* __restrict__ Opart, const u16* __restrict__ y,
                  u16* __restrict__ ysimg) {
    int i = blockIdx.x * 256 + threadIdx.x;
    size_t off = (size_t)i * 4;
    int row = i >> 8, col = (i & 255) * 4;
    u16x4 o0 = *(const u16x4*)&Opart[off];
    u16x4 o1 = *(const u16x4*)&Opart[(size_t)4096 * 1024 + off];
    u16x4 yv = *(const u16x4*)&y[off];
    u16x4 r;
    r.x = f2bf(bf2f(yv.x) + bf2f(o0.x) + bf2f(o1.x));
    r.y = f2bf(bf2f(yv.y) + bf2f(o0.y) + bf2f(o1.y));
    r.z = f2bf(bf2f(yv.z) + bf2f(o0.z) + bf2f(o1.z));
    r.w = f2bf(bf2f(yv.w) + bf2f(o0.w) + bf2f(o1.w));
    *(u16x4*)&ysimg[g64_idx(row, col)] = r;
}

// ---------------------------------------------------------------------------
extern "C" void kernel_launch(void* const* d_in, const int* in_sizes, int n_in,
                              void* d_out, int out_size, void* d_ws, size_t ws_size,
                              hipStream_t stream) {
    const float* x      = (const float*)d_in[0];
    const float* W_attn = (const float*)d_in[1];
    const float* W_k2   = (const float*)d_in[2];
    const float* W_proj = (const float*)d_in[3];
    float* out = (float*)d_out;

    char* w = (char*)d_ws;
    u16* xb      = (u16*)w; w += (size_t)4096 * 1024 * 2;   //  8 MB (reused as ysimg)
    u16* bgimg   = (u16*)w; w += (size_t)3072 * 1024 * 2;   //  6 MB fused-B image
    u16* bpimg   = (u16*)w; w += (size_t)1024 * 1024 * 2;   //  2 MB proj-B image
    u16* qs      = (u16*)w; w += (size_t)4096 * 1024 * 2;   //  8 MB
    u16* kpack   = (u16*)w; w += (size_t)4096 * 1024 * 2;   //  8 MB
    u16* kapack  = (u16*)w; w += (size_t)4096 * 1024 * 2;   //  8 MB
    u16* xpack   = (u16*)w; w += (size_t)4096 * 1024 * 2;   //  8 MB
    u16* y       = (u16*)w; w += (size_t)4096 * 1024 * 2;   //  8 MB
    u16* epack   = (u16*)w; w += (size_t)4096 * 1024 * 2;   //  8 MB
    u16* Opart   = (u16*)w; w += (size_t)2 * 4096 * 1024 * 2; // 16 MB
    float* lpart = (float*)w; w += (size_t)2 * 65536 * 4;   // 0.5 MB (~80.5 MB)
    u16* agimg = Opart;   // 8 MB A-image; dead before flash_mfma writes Opart
    u16* ysimg = xb;      // xb dead after combine_flash

    convert_pack<<<dim3(4096), dim3(256), 0, stream>>>(x, xb, xpack, agimg);
    prep_weights<<<dim3(64, 16), dim3(256), 0, stream>>>(W_attn, W_k2, W_proj,
                                                         bgimg, bpimg);
    gemm_fused<<<dim3(12, 16), dim3(512), 0, stream>>>(agimg, bgimg, qs, kpack, kapack);
    flash_mfma<<<dim3(8, 32, 2), dim3(256), 0, stream>>>(qs, kpack, xpack, Opart, lpart);
    combine_flash<<<dim3(4096), dim3(256), 0, stream>>>(Opart, lpart, xb, y, epack);
    arma_mfma<<<dim3(8, 32, 2), dim3(256), 0, stream>>>(qs, kapack, epack, Opart);
    combine_arma<<<dim3(4096), dim3(256), 0, stream>>>(Opart, y, ysimg);
    gemm64<<<dim3(8, 64), dim3(256), 0, stream>>>(ysimg, bpimg, out, 1024, 1024);
}

// Round 7
// 261.474 us; speedup vs baseline: 1.1456x; 1.1456x over previous
//
#include <hip/hip_runtime.h>

// B=2, T=2048, C=1024, H=16, d=64. Inputs/outputs fp32; internal bf16 MFMA.
typedef unsigned short u16;
typedef u16   u16x4  __attribute__((ext_vector_type(4)));
typedef u16   u16x8  __attribute__((ext_vector_type(8)));
typedef __bf16 bf16x8 __attribute__((ext_vector_type(8)));
typedef float  f32x4  __attribute__((ext_vector_type(4)));

__device__ __forceinline__ float bf2f(u16 v) {
    unsigned u = ((unsigned)v) << 16;
    return __builtin_bit_cast(float, u);
}
__device__ __forceinline__ u16 f2bf(float f) {
    unsigned u = __builtin_bit_cast(unsigned, f);
    u += 0x7fffu + ((u >> 16) & 1u);   // RNE
    return (u16)(u >> 16);
}

// Async global->LDS DMA, 16B per lane. LDS dest is lane-linear
// (wave-uniform base + lane*16B). Global src is image-linear => coalesced.
__device__ __forceinline__ void async16(const u16* g, u16* l) {
    __builtin_amdgcn_global_load_lds(
        (const __attribute__((address_space(1))) unsigned int*)g,
        (__attribute__((address_space(3))) unsigned int*)l,
        16, 0, 0);
}

// Packed operand images: per (bh, 64-s-chunk) a 512-slot x 8-elem tile (4096 u16).
// K-operand image (k=d): slot = (d>>3)*64 + (s&63), elem = d&7
__device__ __forceinline__ size_t kimg_idx(int bh, int s, int d) {
    return ((size_t)(bh * 32 + (s >> 6)) * 4096) + (size_t)(((d >> 3) * 64 + (s & 63)) * 8) + (d & 7);
}
// V-operand image (k=s): slot = ((s&63)>>3)*64 + d, elem = s&7
__device__ __forceinline__ size_t vimg_idx(int bh, int s, int d) {
    return ((size_t)(bh * 32 + (s >> 6)) * 4096) + (size_t)((((s & 63) >> 3) * 64 + d) * 8) + (s & 7);
}

// GEMM DMA-images: per (128-row-tile, 32-k-slab) a contiguous 4096-u16 block
// whose slot order equals the GEMM LDS layout [kk][row] -> coalesced DMA.
__device__ __forceinline__ size_t g128_idx(int m, int k) {
    return ((size_t)((m >> 7) * 32 + (k >> 5)) * 4096)
         + (size_t)((((k >> 3) & 3) * 128 + (m & 127)) * 8 + (k & 7));
}
// BM=64 tiles (A of gemm64): block = 2048 u16.
__device__ __forceinline__ size_t g64_idx(int m, int k) {
    return ((size_t)((m >> 6) * 32 + (k >> 5)) * 2048)
         + (size_t)((((k >> 3) & 3) * 64 + (m & 63)) * 8 + (k & 7));
}

// ---------------------------------------------------------------------------
// fp32 x -> bf16 row-major xb, V-image xpack, GEMM A-image agimg.
// Thread owns 8 consecutive k -> xb and agimg writes are one 16B store each.
// grid 2048.
// ---------------------------------------------------------------------------
__global__ __launch_bounds__(256)
void convert_pack(const float* __restrict__ in, u16* __restrict__ xb,
                  u16* __restrict__ xpack, u16* __restrict__ agimg) {
    int i = blockIdx.x * 256 + threadIdx.x;       // [0, 524288)
    int c8 = i & 127, row = i >> 7;               // row = b*2048 + s
    int s = row & 2047, b = row >> 11;
    float4 v0 = ((const float4*)in)[(size_t)i * 2];
    float4 v1 = ((const float4*)in)[(size_t)i * 2 + 1];
    u16x8 o;
    o[0] = f2bf(v0.x); o[1] = f2bf(v0.y); o[2] = f2bf(v0.z); o[3] = f2bf(v0.w);
    o[4] = f2bf(v1.x); o[5] = f2bf(v1.y); o[6] = f2bf(v1.z); o[7] = f2bf(v1.w);
    ((u16x8*)xb)[i] = o;
    int h = c8 >> 3, d0 = (c8 & 7) * 8;
    size_t base = vimg_idx(b * 16 + h, s, d0);
#pragma unroll
    for (int j = 0; j < 8; ++j) xpack[base + j * 8] = o[j];
    *(u16x8*)&agimg[g128_idx(row, c8 * 8)] = o;   // 16B contiguous
}

// ---------------------------------------------------------------------------
// Weight transposes -> GEMM B-images, coalesced image writes. grid (64,16).
// bgimg: fused-B image over n in [0,3072); bpimg: proj-B image, n in [0,1024).
// Write loop indexed by contiguous image offset u: consecutive threads write
// consecutive u16 (128B runs per wave). LDS read side is the scattered one.
// ---------------------------------------------------------------------------
__global__ __launch_bounds__(256)
void prep_weights(const float* __restrict__ Wa, const float* __restrict__ Wk,
                  const float* __restrict__ Wp, u16* __restrict__ bgimg,
                  u16* __restrict__ bpimg) {
    __shared__ u16 tile[64][65];
    const int bx = blockIdx.x;
    const float* in; u16* img; int Cd, c0, nbase;
    if (bx < 32)      { in = Wa; img = bgimg; Cd = 2048; c0 = bx * 64;        nbase = c0; }
    else if (bx < 48) { in = Wk; img = bgimg; Cd = 1024; c0 = (bx - 32) * 64; nbase = 2048 + c0; }
    else              { in = Wp; img = bpimg; Cd = 1024; c0 = (bx - 48) * 64; nbase = c0; }
    const int r0 = blockIdx.y * 64;               // k-base
    const int tid = threadIdx.x;
#pragma unroll
    for (int i = 0; i < 16; ++i) {
        int idx = tid + i * 256;
        int r = idx >> 6, c = idx & 63;
        tile[r][c] = f2bf(in[(size_t)(r0 + r) * Cd + c0 + c]);   // tile[k][n]
    }
    __syncthreads();
#pragma unroll
    for (int ii = 0; ii < 16; ++ii) {
        int u = tid + ii * 256;                   // [0,4096): 2 k-slabs x 2048
        int s = u >> 11, kk = (u >> 9) & 3, nr = (u >> 3) & 63, e = u & 7;
        int r = s * 32 + kk * 8 + e;              // k-local
        int n = nbase + nr, k = r0 + r;
        size_t o = (size_t)((n >> 7) * 32 + (k >> 5)) * 4096
                 + (size_t)(kk * 1024 + (n & 127) * 8 + e);
        img[o] = tile[r][nr];
    }
}

// ---------------------------------------------------------------------------
// Fused GEMM: [4096 x 3072] = x @ [W_attn ; W_k2] via DMA-images.
// 128x128 tile; global_load_lds from image (coalesced 4KB/issue) into
// triple-buffered linear LDS; depth-2 prefetch, counted vmcnt (never 0 in
// main loop). Per K-step: { vmcnt(4) -> barrier -> issue slab t+2 ->
// ds_read+MFMA buf[t%3] }. LDS 48 KB -> 3 blocks/CU (grid 24x32 = 3/CU).
// Epilogue: n<1024 -> qs*0.125; n<2048 -> kpack; else sigmoid -> kapack.
// ---------------------------------------------------------------------------
__global__ __launch_bounds__(256, 3)
void gemm_fused(const u16* __restrict__ Aimg, const u16* __restrict__ Bimg,
                u16* __restrict__ qs, u16* __restrict__ kpack,
                u16* __restrict__ kapack) {
    const int NT = 32;                               // 1024 / 32
    __shared__ __align__(16) u16 As[3][4][128][8];   // [buf][kk][row][8], 4096 u16/buf
    __shared__ __align__(16) u16 Bs[3][4][128][8];
    const int tid = threadIdx.x;
    const int wave = tid >> 6, lane = tid & 63;
    const int m0 = blockIdx.y * 128, n0 = blockIdx.x * 128;
    const int wm = (wave >> 1) * 64, wn = (wave & 1) * 64;
    const int q = lane >> 4, mr = lane & 15;

    const u16* gA = Aimg + (size_t)blockIdx.y * 32 * 4096;   // m-tile base
    const u16* gB = Bimg + (size_t)blockIdx.x * 32 * 4096;   // n-tile base
    u16* const lA = &As[0][0][0][0];
    u16* const lB = &Bs[0][0][0][0];
    const int d0 = tid * 8, d1 = (256 + tid) * 8;

    f32x4 acc[4][4];
#pragma unroll
    for (int i = 0; i < 4; ++i)
#pragma unroll
        for (int j = 0; j < 4; ++j) acc[i][j] = f32x4{0.f, 0.f, 0.f, 0.f};

    // prologue: slabs 0,1 -> bufs 0,1 (8 DMA ops/wave in flight)
    async16(gA + d0,        lA + d0);
    async16(gA + d1,        lA + d1);
    async16(gB + d0,        lB + d0);
    async16(gB + d1,        lB + d1);
    async16(gA + 4096 + d0, lA + 4096 + d0);
    async16(gA + 4096 + d1, lA + 4096 + d1);
    async16(gB + 4096 + d0, lB + 4096 + d0);
    async16(gB + 4096 + d1, lB + 4096 + d1);

    int co = 0;                  // compute-buffer offset (u16 units)
    int io = 2 * 4096;           // issue-buffer offset
    for (int t = 0; t < NT; ++t) {
        if (t < NT - 1) asm volatile("s_waitcnt vmcnt(4)" ::: "memory");
        else            asm volatile("s_waitcnt vmcnt(0)" ::: "memory");
        __syncthreads();         // slab t visible to all; iter t-1 reads done
        if (t + 2 < NT) {        // issue slab t+2 into buf (t+2)%3
            const int sg = (t + 2) * 4096;
            async16(gA + sg + d0, lA + io + d0);
            async16(gA + sg + d1, lA + io + d1);
            async16(gB + sg + d0, lB + io + d0);
            async16(gB + sg + d1, lB + io + d1);
        }
        bf16x8 af[4], bfr[4];
#pragma unroll
        for (int i = 0; i < 4; ++i)
            af[i]  = *(const bf16x8*)(lA + co + (size_t)(q * 128 + wm + i * 16 + mr) * 8);
#pragma unroll
        for (int j = 0; j < 4; ++j)
            bfr[j] = *(const bf16x8*)(lB + co + (size_t)(q * 128 + wn + j * 16 + mr) * 8);
#pragma unroll
        for (int i = 0; i < 4; ++i)
#pragma unroll
            for (int j = 0; j < 4; ++j)
                acc[i][j] = __builtin_amdgcn_mfma_f32_16x16x32_bf16(af[i], bfr[j], acc[i][j], 0, 0, 0);
        co += 4096; if (co == 3 * 4096) co = 0;
        io += 4096; if (io == 3 * 4096) io = 0;
    }
#pragma unroll
    for (int i = 0; i < 4; ++i)
#pragma unroll
        for (int j = 0; j < 4; ++j)
#pragma unroll
            for (int r = 0; r < 4; ++r) {
                int m = m0 + wm + i * 16 + q * 4 + r;
                int n = n0 + wn + j * 16 + mr;
                float v = acc[i][j][r];
                int b = m >> 11, s = m & 2047;
                if (n < 1024) {
                    qs[(size_t)m * 1024 + n] = f2bf(v * 0.125f);
                } else if (n < 2048) {
                    int nn = n - 1024;
                    kpack[kimg_idx(b * 16 + (nn >> 6), s, nn & 63)] = f2bf(v);
                } else {
                    int nn = n - 2048;
                    kapack[kimg_idx(b * 16 + (nn >> 6), s, nn & 63)] =
                        f2bf(1.f / (1.f + __expf(-0.0025f * v)));
                }
            }
}

// ---------------------------------------------------------------------------
// 64x128-tile GEMM (proj): fp32 row-major out, DMA-image sources. Triple-
// buffered depth-2 counted-vmcnt pipeline (3 ops/slab). grid (8,64).
// ---------------------------------------------------------------------------
__global__ __launch_bounds__(256, 2)
void gemm64(const u16* __restrict__ Aimg, const u16* __restrict__ Bimg,
            float* __restrict__ Cv, int N, int K) {
    const int NT = 32;
    __shared__ __align__(16) u16 As[3][4][64][8];    // 2048 u16/buf
    __shared__ __align__(16) u16 Bs[3][4][128][8];   // 4096 u16/buf
    const int tid = threadIdx.x;
    const int wave = tid >> 6, lane = tid & 63;
    const int m0 = blockIdx.y * 64, n0 = blockIdx.x * 128;
    const int wn0 = wave * 32;
    const int q = lane >> 4, mr = lane & 15;

    const u16* gA = Aimg + (size_t)blockIdx.y * 32 * 2048;
    const u16* gB = Bimg + (size_t)blockIdx.x * 32 * 4096;
    u16* const lA = &As[0][0][0][0];
    u16* const lB = &Bs[0][0][0][0];
    const int d0 = tid * 8, d1 = (256 + tid) * 8;

    f32x4 acc[4][2];
#pragma unroll
    for (int i = 0; i < 4; ++i)
#pragma unroll
        for (int j = 0; j < 2; ++j) acc[i][j] = f32x4{0.f, 0.f, 0.f, 0.f};

    // prologue: slabs 0,1 -> bufs 0,1 (6 DMA ops/wave)
    async16(gA + d0,        lA + d0);
    async16(gB + d0,        lB + d0);
    async16(gB + d1,        lB + d1);
    async16(gA + 2048 + d0, lA + 2048 + d0);
    async16(gB + 4096 + d0, lB + 4096 + d0);
    async16(gB + 4096 + d1, lB + 4096 + d1);

    int coA = 0, coB = 0, ioA = 2 * 2048, ioB = 2 * 4096;
    for (int t = 0; t < NT; ++t) {
        if (t < NT - 1) asm volatile("s_waitcnt vmcnt(3)" ::: "memory");
        else            asm volatile("s_waitcnt vmcnt(0)" ::: "memory");
        __syncthreads();
        if (t + 2 < NT) {
            async16(gA + (t + 2) * 2048 + d0, lA + ioA + d0);
            async16(gB + (t + 2) * 4096 + d0, lB + ioB + d0);
            async16(gB + (t + 2) * 4096 + d1, lB + ioB + d1);
        }
        bf16x8 af[4], bfr[2];
#pragma unroll
        for (int i = 0; i < 4; ++i)
            af[i]  = *(const bf16x8*)(lA + coA + (size_t)(q * 64 + i * 16 + mr) * 8);
#pragma unroll
        for (int j = 0; j < 2; ++j)
            bfr[j] = *(const bf16x8*)(lB + coB + (size_t)(q * 128 + wn0 + j * 16 + mr) * 8);
#pragma unroll
        for (int i = 0; i < 4; ++i)
#pragma unroll
            for (int j = 0; j < 2; ++j)
                acc[i][j] = __builtin_amdgcn_mfma_f32_16x16x32_bf16(af[i], bfr[j], acc[i][j], 0, 0, 0);
        coA += 2048; if (coA == 3 * 2048) coA = 0;
        coB += 4096; if (coB == 3 * 4096) coB = 0;
        ioA += 2048; if (ioA == 3 * 2048) ioA = 0;
        ioB += 4096; if (ioB == 3 * 4096) ioB = 0;
    }
#pragma unroll
    for (int i = 0; i < 4; ++i)
#pragma unroll
        for (int j = 0; j < 2; ++j)
#pragma unroll
            for (int r = 0; r < 4; ++r) {
                int m = m0 + i * 16 + q * 4 + r;
                int n = n0 + wn0 + j * 16 + mr;
                Cv[(size_t)m * N + n] = acc[i][j][r];
            }
}

// ---------------------------------------------------------------------------
// Flash attention: 128-row t-tiles (2 m-tiles/wave: {w, w+4}), s-split (z =
// chunk parity). Block bx handles tile pair {bx, 15-bx}. Static mt unroll
// (dynamic bounds caused scratch demotion in R7).
// ---------------------------------------------------------------------------
__global__ __launch_bounds__(256, 2)
void flash_mfma(const u16* __restrict__ qs, const u16* __restrict__ kpack,
                const u16* __restrict__ xpack, u16* __restrict__ Opart,
                float* __restrict__ lpart) {
    __shared__ __align__(16) u16 Ks[8][64][8];
    __shared__ __align__(16) u16 Vs[8][64][8];
    __shared__ __align__(16) u16 Ps[4][16][72];
    const int bh = blockIdx.y, b = bh >> 4, hc = (bh & 15) * 64;
    const int z = blockIdx.z;
    const int tid = threadIdx.x, w = tid >> 6, lane = tid & 63;
    const int n16 = lane & 15, quad = lane >> 4;
    const u16* kbase = kpack + (size_t)bh * 32 * 4096;
    const u16* vbase = xpack + (size_t)bh * 32 * 4096;
    u16* Ob = Opart + (size_t)z * 4096 * 1024;
    float* lb = lpart + z * 65536;

    for (int rep = 0; rep < 2; ++rep) {
        const int T = rep ? 15 - (int)blockIdx.x : (int)blockIdx.x;
        const int t0 = T * 128;
        const int nchunk = 2 * T + 2;

        bf16x8 qf[2][2];
#pragma unroll
        for (int mt = 0; mt < 2; ++mt) {
            const int trow = t0 + (w + mt * 4) * 16 + n16;
            const u16* qp = &qs[(size_t)(b * 2048 + trow) * 1024 + hc + quad * 8];
            qf[mt][0] = *(const bf16x8*)qp;
            qf[mt][1] = *(const bf16x8*)(qp + 32);
        }

        f32x4 O[2][4];
        float lsum[2][4];
#pragma unroll
        for (int mt = 0; mt < 2; ++mt)
#pragma unroll
            for (int jt = 0; jt < 4; ++jt) { O[mt][jt] = f32x4{0.f, 0.f, 0.f, 0.f}; }
#pragma unroll
        for (int mt = 0; mt < 2; ++mt)
#pragma unroll
            for (int r = 0; r < 4; ++r) lsum[mt][r] = 0.f;

        u16x8 kr0, kr1, vr0, vr1;
        auto pref = [&](int c) {
            const u16* kc = kbase + (size_t)c * 4096;
            const u16* vc = vbase + (size_t)c * 4096;
            kr0 = *(const u16x8*)(kc + tid * 8);
            kr1 = *(const u16x8*)(kc + (256 + tid) * 8);
            vr0 = *(const u16x8*)(vc + tid * 8);
            vr1 = *(const u16x8*)(vc + (256 + tid) * 8);
        };
        if (z < nchunk) pref(z);

        for (int c = z; c < nchunk; c += 2) {
            __syncthreads();
            *(u16x8*)((u16*)Ks + tid * 8)         = kr0;
            *(u16x8*)((u16*)Ks + (256 + tid) * 8) = kr1;
            *(u16x8*)((u16*)Vs + tid * 8)         = vr0;
            *(u16x8*)((u16*)Vs + (256 + tid) * 8) = vr1;
            __syncthreads();
            if (c + 2 < nchunk) pref(c + 2);

            f32x4 S[2][4];
#pragma unroll
            for (int mt = 0; mt < 2; ++mt)
#pragma unroll
                for (int jt = 0; jt < 4; ++jt) S[mt][jt] = f32x4{0.f, 0.f, 0.f, 0.f};
#pragma unroll
            for (int ks = 0; ks < 2; ++ks)
#pragma unroll
                for (int jt = 0; jt < 4; ++jt) {
                    bf16x8 kf = *(const bf16x8*)&Ks[ks * 4 + quad][jt * 16 + n16][0];
                    S[0][jt] = __builtin_amdgcn_mfma_f32_16x16x32_bf16(qf[0][ks], kf, S[0][jt], 0, 0, 0);
                    S[1][jt] = __builtin_amdgcn_mfma_f32_16x16x32_bf16(qf[1][ks], kf, S[1][jt], 0, 0, 0);
                }
            bf16x8 vf[2][4];
#pragma unroll
            for (int ks = 0; ks < 2; ++ks)
#pragma unroll
                for (int jt = 0; jt < 4; ++jt)
                    vf[ks][jt] = *(const bf16x8*)&Vs[ks * 4 + quad][jt * 16 + n16][0];

#pragma unroll
            for (int mt = 0; mt < 2; ++mt) {
                if (mt == 0 && c == 2 * T + 1) continue;   // fully-masked subtile
                float p[4][4];
#pragma unroll
                for (int reg = 0; reg < 4; ++reg)
#pragma unroll
                    for (int jt = 0; jt < 4; ++jt)
                        p[reg][jt] = __expf(S[mt][jt][reg]);
                if (c == 2 * T + mt) {   // partially-masked diagonal subtile
#pragma unroll
                    for (int reg = 0; reg < 4; ++reg) {
                        const int tr = t0 + (w + mt * 4) * 16 + quad * 4 + reg;
#pragma unroll
                        for (int jt = 0; jt < 4; ++jt)
                            if (c * 64 + jt * 16 + n16 > tr) p[reg][jt] = 0.f;
                    }
                }
#pragma unroll
                for (int reg = 0; reg < 4; ++reg) {
                    lsum[mt][reg] += (p[reg][0] + p[reg][1]) + (p[reg][2] + p[reg][3]);
#pragma unroll
                    for (int jt = 0; jt < 4; ++jt)
                        Ps[w][quad * 4 + reg][jt * 16 + n16] = f2bf(p[reg][jt]);
                }
                bf16x8 pf[2];
#pragma unroll
                for (int ks = 0; ks < 2; ++ks)
                    pf[ks] = *(const bf16x8*)&Ps[w][n16][ks * 32 + quad * 8];
#pragma unroll
                for (int ks = 0; ks < 2; ++ks)
#pragma unroll
                    for (int jt = 0; jt < 4; ++jt)
                        O[mt][jt] = __builtin_amdgcn_mfma_f32_16x16x32_bf16(pf[ks], vf[ks][jt], O[mt][jt], 0, 0, 0);
            }
        }

#pragma unroll
        for (int mt = 0; mt < 2; ++mt)
#pragma unroll
            for (int reg = 0; reg < 4; ++reg) {
                float l = lsum[mt][reg];
#pragma unroll
                for (int off = 1; off < 16; off <<= 1) l += __shfl_xor(l, off, 64);
                const int tr = t0 + (w + mt * 4) * 16 + quad * 4 + reg;
                if (n16 == 0) lb[bh * 2048 + tr] = l;
                const size_t row = (size_t)(b * 2048 + tr) * 1024 + hc;
#pragma unroll
                for (int jt = 0; jt < 4; ++jt)
                    Ob[row + jt * 16 + n16] = f2bf(O[mt][jt][reg]);
            }
    }
}

// ---------------------------------------------------------------------------
// combine flash halves: y = (O0+O1)/(l0+l1); epack = V-image of x[t+1]-y[t].
// ---------------------------------------------------------------------------
__global__ __launch_bounds__(256)
void combine_flash(const u16* __restrict__ Opart, const float* __restrict__ lpart,
                   const u16* __restrict__ xb, u16* __restrict__ y,
                   u16* __restrict__ epack) {
    int i = blockIdx.x * 256 + threadIdx.x;
    int c4 = i & 255, row = i >> 8, t = row & 2047, b = row >> 11;
    int h = c4 >> 4, d0 = (c4 & 15) * 4;
    size_t off = (size_t)row * 1024 + c4 * 4;
    u16x4 o0 = *(const u16x4*)&Opart[off];
    u16x4 o1 = *(const u16x4*)&Opart[(size_t)4096 * 1024 + off];
    int lrow = (b * 16 + h) * 2048 + t;
    float inv = 1.f / (lpart[lrow] + lpart[65536 + lrow]);
    float y0 = (bf2f(o0.x) + bf2f(o1.x)) * inv;
    float y1 = (bf2f(o0.y) + bf2f(o1.y)) * inv;
    float y2 = (bf2f(o0.z) + bf2f(o1.z)) * inv;
    float y3 = (bf2f(o0.w) + bf2f(o1.w)) * inv;
    u16x4 yo;
    yo.x = f2bf(y0); yo.y = f2bf(y1); yo.z = f2bf(y2); yo.w = f2bf(y3);
    *(u16x4*)&y[off] = yo;
    float e0 = 0.f, e1 = 0.f, e2 = 0.f, e3 = 0.f;
    if (t < 2047) {
        u16x4 xv = *(const u16x4*)&xb[off + 1024];
        e0 = bf2f(xv.x) - y0; e1 = bf2f(xv.y) - y1;
        e2 = bf2f(xv.z) - y2; e3 = bf2f(xv.w) - y3;
    }
    size_t base = vimg_idx(b * 16 + h, t, d0);
    epack[base]      = f2bf(e0);
    epack[base + 8]  = f2bf(e1);
    epack[base + 16] = f2bf(e2);
    epack[base + 24] = f2bf(e3);
}

// ---------------------------------------------------------------------------
// ARMA, same 128-row structure, strict mask, no softmax. Static mt unroll.
// ---------------------------------------------------------------------------
__global__ __launch_bounds__(256, 2)
void arma_mfma(const u16* __restrict__ qs, const u16* __restrict__ kapack,
               const u16* __restrict__ epack, u16* __restrict__ Opart) {
    __shared__ __align__(16) u16 Ks[8][64][8];
    __shared__ __align__(16) u16 Es[8][64][8];
    __shared__ __align__(16) u16 Ps[4][16][72];
    const int bh = blockIdx.y, b = bh >> 4, hc = (bh & 15) * 64;
    const int z = blockIdx.z;
    const int tid = threadIdx.x, w = tid >> 6, lane = tid & 63;
    const int n16 = lane & 15, quad = lane >> 4;
    const u16* kbase = kapack + (size_t)bh * 32 * 4096;
    const u16* vbase = epack + (size_t)bh * 32 * 4096;
    u16* Ob = Opart + (size_t)z * 4096 * 1024;

    for (int rep = 0; rep < 2; ++rep) {
        const int T = rep ? 15 - (int)blockIdx.x : (int)blockIdx.x;
        const int t0 = T * 128;
        const int nchunk = 2 * T + 2;

        bf16x8 qf[2][2];
#pragma unroll
        for (int mt = 0; mt < 2; ++mt) {
            const int trow = t0 + (w + mt * 4) * 16 + n16;
            const u16* qp = &qs[(size_t)(b * 2048 + trow) * 1024 + hc + quad * 8];
#pragma unroll
            for (int ks = 0; ks < 2; ++ks) {
                u16x8 qv = *(const u16x8*)(qp + ks * 32);
                u16x8 o;
#pragma unroll
                for (int j = 0; j < 8; ++j) {
                    float zv = bf2f(qv[j]);              // pre-scaled by 1/8
                    o[j] = f2bf(zv < 0.f ? zv : 0.02f * zv);
                }
                qf[mt][ks] = __builtin_bit_cast(bf16x8, o);
            }
        }

        f32x4 O[2][4];
#pragma unroll
        for (int mt = 0; mt < 2; ++mt)
#pragma unroll
            for (int jt = 0; jt < 4; ++jt) O[mt][jt] = f32x4{0.f, 0.f, 0.f, 0.f};

        u16x8 kr0, kr1, vr0, vr1;
        auto pref = [&](int c) {
            const u16* kc = kbase + (size_t)c * 4096;
            const u16* vc = vbase + (size_t)c * 4096;
            kr0 = *(const u16x8*)(kc + tid * 8);
            kr1 = *(const u16x8*)(kc + (256 + tid) * 8);
            vr0 = *(const u16x8*)(vc + tid * 8);
            vr1 = *(const u16x8*)(vc + (256 + tid) * 8);
        };
        if (z < nchunk) pref(z);

        for (int c = z; c < nchunk; c += 2) {
            __syncthreads();
            *(u16x8*)((u16*)Ks + tid * 8)         = kr0;
            *(u16x8*)((u16*)Ks + (256 + tid) * 8) = kr1;
            *(u16x8*)((u16*)Es + tid * 8)         = vr0;
            *(u16x8*)((u16*)Es + (256 + tid) * 8) = vr1;
            __syncthreads();
            if (c + 2 < nchunk) pref(c + 2);

            f32x4 S[2][4];
#pragma unroll
            for (int mt = 0; mt < 2; ++mt)
#pragma unroll
                for (int jt = 0; jt < 4; ++jt) S[mt][jt] = f32x4{0.f, 0.f, 0.f, 0.f};
#pragma unroll
            for (int ks = 0; ks < 2; ++ks)
#pragma unroll
                for (int jt = 0; jt < 4; ++jt) {
                    bf16x8 kf = *(const bf16x8*)&Ks[ks * 4 + quad][jt * 16 + n16][0];
                    S[0][jt] = __builtin_amdgcn_mfma_f32_16x16x32_bf16(qf[0][ks], kf, S[0][jt], 0, 0, 0);
                    S[1][jt] = __builtin_amdgcn_mfma_f32_16x16x32_bf16(qf[1][ks], kf, S[1][jt], 0, 0, 0);
                }
            bf16x8 vf[2][4];
#pragma unroll
            for (int ks = 0; ks < 2; ++ks)
#pragma unroll
                for (int jt = 0; jt < 4; ++jt)
                    vf[ks][jt] = *(const bf16x8*)&Es[ks * 4 + quad][jt * 16 + n16][0];

#pragma unroll
            for (int mt = 0; mt < 2; ++mt) {
                if (mt == 0 && c == 2 * T + 1) continue;   // fully-masked subtile
                if (c == 2 * T + mt) {   // strict mask s < t on diagonal subtile
#pragma unroll
                    for (int reg = 0; reg < 4; ++reg) {
                        const int tr = t0 + (w + mt * 4) * 16 + quad * 4 + reg;
#pragma unroll
                        for (int jt = 0; jt < 4; ++jt)
                            if (c * 64 + jt * 16 + n16 >= tr) S[mt][jt][reg] = 0.f;
                    }
                }
#pragma unroll
                for (int reg = 0; reg < 4; ++reg)
#pragma unroll
                    for (int jt = 0; jt < 4; ++jt)
                        Ps[w][quad * 4 + reg][jt * 16 + n16] = f2bf(S[mt][jt][reg]);
                bf16x8 pf[2];
#pragma unroll
                for (int ks = 0; ks < 2; ++ks)
                    pf[ks] = *(const bf16x8*)&Ps[w][n16][ks * 32 + quad * 8];
#pragma unroll
                for (int ks = 0; ks < 2; ++ks)
#pragma unroll
                    for (int jt = 0; jt < 4; ++jt)
                        O[mt][jt] = __builtin_amdgcn_mfma_f32_16x16x32_bf16(pf[ks], vf[ks][jt], O[mt][jt], 0, 0, 0);
            }
        }

#pragma unroll
        for (int mt = 0; mt < 2; ++mt)
#pragma unroll
            for (int reg = 0; reg < 4; ++reg) {
                const int tr = t0 + (w + mt * 4) * 16 + quad * 4 + reg;
                const size_t row = (size_t)(b * 2048 + tr) * 1024 + hc;
#pragma unroll
                for (int jt = 0; jt < 4; ++jt)
                    Ob[row + jt * 16 + n16] = f2bf(O[mt][jt][reg]);
            }
    }
}

// ---------------------------------------------------------------------------
// combine arma halves: ysimg = A-image (BM=64) of y + O0 + O1 (bf16).
// Thread owns 8 consecutive cols -> all reads/writes 16B contiguous. grid 2048.
// ---------------------------------------------------------------------------
__global__ __launch_bounds__(256)
void combine_arma(const u16* __restrict__ Opart, const u16* __restrict__ y,
                  u16* __restrict__ ysimg) {
    int i = blockIdx.x * 256 + threadIdx.x;       // [0, 524288)
    int c8 = i & 127, row = i >> 7;
    size_t off = (size_t)i * 8;
    u16x8 o0 = *(const u16x8*)&Opart[off];
    u16x8 o1 = *(const u16x8*)&Opart[(size_t)4096 * 1024 + off];
    u16x8 yv = *(const u16x8*)&y[off];
    u16x8 r;
#pragma unroll
    for (int j = 0; j < 8; ++j)
        r[j] = f2bf(bf2f(yv[j]) + bf2f(o0[j]) + bf2f(o1[j]));
    *(u16x8*)&ysimg[g64_idx(row, c8 * 8)] = r;    // 16B contiguous
}

// ---------------------------------------------------------------------------
extern "C" void kernel_launch(void* const* d_in, const int* in_sizes, int n_in,
                              void* d_out, int out_size, void* d_ws, size_t ws_size,
                              hipStream_t stream) {
    const float* x      = (const float*)d_in[0];
    const float* W_attn = (const float*)d_in[1];
    const float* W_k2   = (const float*)d_in[2];
    const float* W_proj = (const float*)d_in[3];
    float* out = (float*)d_out;

    char* w = (char*)d_ws;
    u16* xb      = (u16*)w; w += (size_t)4096 * 1024 * 2;   //  8 MB (reused as ysimg)
    u16* bgimg   = (u16*)w; w += (size_t)3072 * 1024 * 2;   //  6 MB fused-B image
    u16* bpimg   = (u16*)w; w += (size_t)1024 * 1024 * 2;   //  2 MB proj-B image
    u16* qs      = (u16*)w; w += (size_t)4096 * 1024 * 2;   //  8 MB
    u16* kpack   = (u16*)w; w += (size_t)4096 * 1024 * 2;   //  8 MB
    u16* kapack  = (u16*)w; w += (size_t)4096 * 1024 * 2;   //  8 MB
    u16* xpack   = (u16*)w; w += (size_t)4096 * 1024 * 2;   //  8 MB
    u16* y       = (u16*)w; w += (size_t)4096 * 1024 * 2;   //  8 MB
    u16* epack   = (u16*)w; w += (size_t)4096 * 1024 * 2;   //  8 MB
    u16* Opart   = (u16*)w; w += (size_t)2 * 4096 * 1024 * 2; // 16 MB
    float* lpart = (float*)w; w += (size_t)2 * 65536 * 4;   // 0.5 MB (~80.5 MB)
    u16* agimg = Opart;   // 8 MB A-image; dead before flash_mfma writes Opart
    u16* ysimg = xb;      // xb dead after combine_flash

    convert_pack<<<dim3(2048), dim3(256), 0, stream>>>(x, xb, xpack, agimg);
    prep_weights<<<dim3(64, 16), dim3(256), 0, stream>>>(W_attn, W_k2, W_proj,
                                                         bgimg, bpimg);
    gemm_fused<<<dim3(24, 32), dim3(256), 0, stream>>>(agimg, bgimg, qs, kpack, kapack);
    flash_mfma<<<dim3(8, 32, 2), dim3(256), 0, stream>>>(qs, kpack, xpack, Opart, lpart);
    combine_flash<<<dim3(4096), dim3(256), 0, stream>>>(Opart, lpart, xb, y, epack);
    arma_mfma<<<dim3(8, 32, 2), dim3(256), 0, stream>>>(qs, kapack, epack, Opart);
    combine_arma<<<dim3(2048), dim3(256), 0, stream>>>(Opart, y, ysimg);
    gemm64<<<dim3(8, 64), dim3(256), 0, stream>>>(ysimg, bpimg, out, 1024, 1024);
}